// Round 7
// baseline (711.870 us; speedup 1.0000x reference)
//
#include <hip/hip_runtime.h>

constexpr float NEG_SLOPE = 0.2f;
constexpr float EPS = 1e-16f;
constexpr float NEG_INF = -1e30f;

// ================= CSR build (self-loop slot = LAST slot of each node) ======

__global__ void count_k(const int* __restrict__ dst, int* __restrict__ cnt, int E) {
    int i = blockIdx.x * blockDim.x + threadIdx.x;
    if (i < E) atomicAdd(&cnt[dst[i]], 1);
}

__global__ void scan1_k(const int* __restrict__ in, int* __restrict__ out,
                        int* __restrict__ bsum, int n) {
    __shared__ int s[256];
    int tid = threadIdx.x;
    int i = blockIdx.x * 256 + tid;
    int v = (i < n) ? in[i] + 1 : 0;   // +1 self-loop slot
    s[tid] = v;
    __syncthreads();
    #pragma unroll
    for (int off = 1; off < 256; off <<= 1) {
        int t = (tid >= off) ? s[tid - off] : 0;
        __syncthreads();
        s[tid] += t;
        __syncthreads();
    }
    if (i < n) out[i] = s[tid] - v;
    if (tid == 255) bsum[blockIdx.x] = s[255];
}

__global__ void scan2_k(int* __restrict__ bsum, int nb) {
    __shared__ int s[1024];
    int tid = threadIdx.x;
    int v = (tid < nb) ? bsum[tid] : 0;
    s[tid] = v;
    __syncthreads();
    #pragma unroll
    for (int off = 1; off < 1024; off <<= 1) {
        int t = (tid >= off) ? s[tid - off] : 0;
        __syncthreads();
        s[tid] += t;
        __syncthreads();
    }
    if (tid < nb) bsum[tid] = s[tid] - v;
}

__global__ void scan3_k(int* __restrict__ rowptr, const int* __restrict__ bsum,
                        int n, int M) {
    int i = blockIdx.x * 256 + threadIdx.x;
    if (i < n) rowptr[i] += bsum[blockIdx.x];
    if (i == 0) rowptr[n] = M;
}

__global__ void fill_k(const int* __restrict__ src, const int* __restrict__ dst,
                       const int* __restrict__ rowptr, int* __restrict__ fill,
                       int* __restrict__ ssrc, int* __restrict__ sdst,
                       int* __restrict__ seid, int E) {
    int i = blockIdx.x * blockDim.x + threadIdx.x;
    if (i < E) {
        int d = dst[i];
        int pos = rowptr[d] + atomicAdd(&fill[d], 1);
        ssrc[pos] = src[i];
        sdst[pos] = d;
        seid[pos] = i;        // self slots stay -1 (memset 0xFF)
    }
}

// permute edge_attr into CSR slot order; self slots (seid<0) skipped here,
// filled by mean_k.
__global__ void permute_k(const float* __restrict__ ea, const int* __restrict__ seid,
                          float* __restrict__ eperm, int M) {
    int t = blockIdx.x * blockDim.x + threadIdx.x;   // t = k*4 + c
    if (t >= M * 4) return;
    int k = t >> 2, c = t & 3;
    int eid = seid[k];
    if (eid < 0) return;
    const float4* srcr = reinterpret_cast<const float4*>(ea) + (size_t)eid * 4;
    reinterpret_cast<float4*>(eperm)[(size_t)k * 4 + c] = srcr[c];
}

template <int PERM>
__global__ void mean_k(const float* __restrict__ ea, const int* __restrict__ seid,
                       const int* __restrict__ rowptr,
                       float* __restrict__ eperm, float* __restrict__ mattr,
                       int* __restrict__ ssrc, int* __restrict__ sdst, int N) {
    int t = blockIdx.x * blockDim.x + threadIdx.x;
    if (t >= N * 16) return;
    int v = t >> 4, f = t & 15;
    int s = rowptr[v], sEnd = rowptr[v + 1] - 1;   // real edges in [s, sEnd)
    float sum = 0.f;
    for (int k = s; k < sEnd; k++) {
        size_t row = PERM ? (size_t)k : (size_t)seid[k];
        sum += PERM ? eperm[row * 16 + f] : ea[row * 16 + f];
    }
    int c = sEnd - s;
    float mean = sum / (float)(c > 1 ? c : 1);
    if (PERM) eperm[(size_t)sEnd * 16 + f] = mean;
    else      mattr[(size_t)v * 16 + f] = mean;
    if (f == 0) { ssrc[sEnd] = v; sdst[sEnd] = v; }
}

// ============= node transforms: xl = x@Wl+bl, xr = x@Wr+br ==================

__global__ __launch_bounds__(256) void xfrm_k(
        const float* __restrict__ x,
        const float* __restrict__ Wl, const float* __restrict__ bl,
        const float* __restrict__ Wr, const float* __restrict__ br,
        float* __restrict__ xl, float* __restrict__ xr, int N) {
    __shared__ float sWl[64 * 64];
    __shared__ float sWr[64 * 64];
    for (int i = threadIdx.x; i < 64 * 64; i += 256) {
        sWl[i] = Wl[i];
        sWr[i] = Wr[i];
    }
    __syncthreads();
    int v = blockIdx.x * 4 + (threadIdx.x >> 6);
    int h = threadIdx.x & 63;
    if (v >= N) return;
    const float4* xrow = reinterpret_cast<const float4*>(x + (size_t)v * 64);
    float al = bl[h], ar = br[h];
    #pragma unroll
    for (int d4 = 0; d4 < 16; d4++) {
        float4 xv = xrow[d4];
        int d = d4 * 4;
        al = fmaf(xv.x, sWl[(d + 0) * 64 + h], al);
        al = fmaf(xv.y, sWl[(d + 1) * 64 + h], al);
        al = fmaf(xv.z, sWl[(d + 2) * 64 + h], al);
        al = fmaf(xv.w, sWl[(d + 3) * 64 + h], al);
        ar = fmaf(xv.x, sWr[(d + 0) * 64 + h], ar);
        ar = fmaf(xv.y, sWr[(d + 1) * 64 + h], ar);
        ar = fmaf(xv.z, sWr[(d + 2) * 64 + h], ar);
        ar = fmaf(xv.w, sWr[(d + 3) * 64 + h], ar);
    }
    xl[(size_t)v * 64 + h] = al;
    xr[(size_t)v * 64 + h] = ar;
}

// ================= Pass A: per-slot scores, LANE = EDGE =====================
// Each lane owns 2 slots; reduction over the 64 features happens in a scalar
// register accumulator — no cross-lane ops at all. We/att broadcast from LDS.

template <int PERM>
__global__ __launch_bounds__(256) void escore_k(
        const float* __restrict__ xl, const float* __restrict__ xr,
        const float* __restrict__ eperm,   // CSR-ordered attrs (PERM=1)
        const float* __restrict__ earaw, const int* __restrict__ seid,
        const float* __restrict__ mattr,
        const int* __restrict__ ssrc, const int* __restrict__ sdst,
        const float* __restrict__ We, const float* __restrict__ att,
        float* __restrict__ escr, int M) {
    __shared__ float4 sWe[16 * 16];   // [d][j] = We[d][4j..4j+3]
    __shared__ float4 sAtt[16];
    int tid = threadIdx.x;
    {
        const float4* We4 = reinterpret_cast<const float4*>(We);
        if (tid < 256) sWe[tid] = We4[tid];
        if (tid < 16) sAtt[tid] = reinterpret_cast<const float4*>(att)[tid];
    }
    __syncthreads();

    int lane = tid & 63;
    int base = (blockIdx.x * 4 + (tid >> 6)) * 128;
    if (base >= M) return;
    int k0 = base + lane;
    int k1 = k0 + 64;
    int k0c = min(k0, M - 1);
    int k1c = min(k1, M - 1);

    int s0 = ssrc[k0c], d0 = sdst[k0c];
    int s1 = ssrc[k1c], d1 = sdst[k1c];

    const float4* rp0;
    const float4* rp1;
    if (PERM) {
        rp0 = reinterpret_cast<const float4*>(eperm) + (size_t)k0c * 4;
        rp1 = reinterpret_cast<const float4*>(eperm) + (size_t)k1c * 4;
    } else {
        int e0 = seid[k0c], e1 = seid[k1c];
        rp0 = (e0 < 0) ? reinterpret_cast<const float4*>(mattr) + (size_t)d0 * 4
                       : reinterpret_cast<const float4*>(earaw) + (size_t)e0 * 4;
        rp1 = (e1 < 0) ? reinterpret_cast<const float4*>(mattr) + (size_t)d1 * 4
                       : reinterpret_cast<const float4*>(earaw) + (size_t)e1 * 4;
    }

    float ea0[16], ea1[16];
    #pragma unroll
    for (int q = 0; q < 4; q++) {
        float4 a = rp0[q];
        ea0[q * 4 + 0] = a.x; ea0[q * 4 + 1] = a.y;
        ea0[q * 4 + 2] = a.z; ea0[q * 4 + 3] = a.w;
        float4 b = rp1[q];
        ea1[q * 4 + 0] = b.x; ea1[q * 4 + 1] = b.y;
        ea1[q * 4 + 2] = b.z; ea1[q * 4 + 3] = b.w;
    }

    const float4* xl4 = reinterpret_cast<const float4*>(xl);
    const float4* xr4 = reinterpret_cast<const float4*>(xr);
    size_t xs0 = (size_t)s0 * 16, xd0 = (size_t)d0 * 16;
    size_t xs1 = (size_t)s1 * 16, xd1 = (size_t)d1 * 16;

    float acc0 = 0.f, acc1 = 0.f;
    #pragma unroll 4
    for (int j = 0; j < 16; ++j) {
        float4 x0 = xl4[xs0 + j];
        float4 r0 = xr4[xd0 + j];
        float4 x1 = xl4[xs1 + j];
        float4 r1 = xr4[xd1 + j];
        float4 ee0 = {0.f, 0.f, 0.f, 0.f};
        float4 ee1 = {0.f, 0.f, 0.f, 0.f};
        #pragma unroll
        for (int d = 0; d < 16; ++d) {
            float4 w = sWe[d * 16 + j];
            float a0 = ea0[d], a1 = ea1[d];
            ee0.x = fmaf(a0, w.x, ee0.x);
            ee0.y = fmaf(a0, w.y, ee0.y);
            ee0.z = fmaf(a0, w.z, ee0.z);
            ee0.w = fmaf(a0, w.w, ee0.w);
            ee1.x = fmaf(a1, w.x, ee1.x);
            ee1.y = fmaf(a1, w.y, ee1.y);
            ee1.z = fmaf(a1, w.z, ee1.z);
            ee1.w = fmaf(a1, w.w, ee1.w);
        }
        float4 a4 = sAtt[j];
        float m;
        m = x0.x + r0.x + ee0.x; m = (m > 0.f) ? m : NEG_SLOPE * m; acc0 = fmaf(a4.x, m, acc0);
        m = x0.y + r0.y + ee0.y; m = (m > 0.f) ? m : NEG_SLOPE * m; acc0 = fmaf(a4.y, m, acc0);
        m = x0.z + r0.z + ee0.z; m = (m > 0.f) ? m : NEG_SLOPE * m; acc0 = fmaf(a4.z, m, acc0);
        m = x0.w + r0.w + ee0.w; m = (m > 0.f) ? m : NEG_SLOPE * m; acc0 = fmaf(a4.w, m, acc0);
        m = x1.x + r1.x + ee1.x; m = (m > 0.f) ? m : NEG_SLOPE * m; acc1 = fmaf(a4.x, m, acc1);
        m = x1.y + r1.y + ee1.y; m = (m > 0.f) ? m : NEG_SLOPE * m; acc1 = fmaf(a4.y, m, acc1);
        m = x1.z + r1.z + ee1.z; m = (m > 0.f) ? m : NEG_SLOPE * m; acc1 = fmaf(a4.z, m, acc1);
        m = x1.w + r1.w + ee1.w; m = (m > 0.f) ? m : NEG_SLOPE * m; acc1 = fmaf(a4.w, m, acc1);
    }
    if (k0 < M) escr[k0] = acc0;
    if (k1 < M) escr[k1] = acc1;
}

// ================= Pass B: softmax + weighted aggregation ===================

__device__ __forceinline__ float rdlanef(float x, int j) {
    return __int_as_float(__builtin_amdgcn_readlane(__float_as_int(x), j));
}

template <int MODE>
__global__ __launch_bounds__(256) void aggregate_k(
        const float* __restrict__ xl, const float* __restrict__ escr,
        const int* __restrict__ ssrc, const int* __restrict__ rowptr,
        const float* __restrict__ bc,
        float* __restrict__ hout,
        const float* __restrict__ h1, const float* __restrict__ Wout,
        const float* __restrict__ bout, float* __restrict__ out, int N) {
    int lane = threadIdx.x & 63;
    int v = blockIdx.x * 4 + (threadIdx.x >> 6);
    if (v >= N) return;

    int s = rowptr[v], e = rowptr[v + 1];
    int deg = e - s;
    float acc;

    if (deg <= 64) {
        // ---- fast path: all scores fit one wave
        int idx = s + lane;
        bool valid = lane < deg;
        float sc = valid ? escr[idx] : NEG_INF;
        float m = sc;
        #pragma unroll
        for (int off = 32; off; off >>= 1) m = fmaxf(m, __shfl_xor(m, off));
        float t = valid ? __expf(sc - m) : 0.f;
        float dsum = t;
        #pragma unroll
        for (int off = 32; off; off >>= 1) dsum += __shfl_xor(dsum, off);
        float alpha = t / (dsum + EPS);
        int srcn = valid ? ssrc[idx] : 0;

        float a0 = 0.f, a1 = 0.f, a2 = 0.f, a3 = 0.f;
        int j = 0;
        for (; j + 4 <= deg; j += 4) {
            int sj0 = __builtin_amdgcn_readlane(srcn, j);
            int sj1 = __builtin_amdgcn_readlane(srcn, j + 1);
            int sj2 = __builtin_amdgcn_readlane(srcn, j + 2);
            int sj3 = __builtin_amdgcn_readlane(srcn, j + 3);
            float w0 = rdlanef(alpha, j);
            float w1 = rdlanef(alpha, j + 1);
            float w2 = rdlanef(alpha, j + 2);
            float w3 = rdlanef(alpha, j + 3);
            a0 = fmaf(w0, xl[(size_t)sj0 * 64 + lane], a0);
            a1 = fmaf(w1, xl[(size_t)sj1 * 64 + lane], a1);
            a2 = fmaf(w2, xl[(size_t)sj2 * 64 + lane], a2);
            a3 = fmaf(w3, xl[(size_t)sj3 * 64 + lane], a3);
        }
        for (; j < deg; ++j) {
            int sj = __builtin_amdgcn_readlane(srcn, j);
            float wj = rdlanef(alpha, j);
            a0 = fmaf(wj, xl[(size_t)sj * 64 + lane], a0);
        }
        acc = (a0 + a1) + (a2 + a3);
    } else {
        // ---- general path (rare): chunked
        float m = NEG_INF;
        for (int b = s; b < e; b += 64) {
            int idx = b + lane;
            float val = (idx < e) ? escr[idx] : NEG_INF;
            #pragma unroll
            for (int off = 32; off; off >>= 1) val = fmaxf(val, __shfl_xor(val, off));
            m = fmaxf(m, val);
        }
        float denom = 0.f;
        for (int b = s; b < e; b += 64) {
            int idx = b + lane;
            float t = (idx < e) ? __expf(escr[idx] - m) : 0.f;
            #pragma unroll
            for (int off = 32; off; off >>= 1) t += __shfl_xor(t, off);
            denom += t;
        }
        float inv = 1.f / (denom + EPS);
        acc = 0.f;
        for (int b = s; b < e; b += 64) {
            int idx = b + lane;
            float wv = (idx < e) ? __expf(escr[idx] - m) * inv : 0.f;
            int srcn = (idx < e) ? ssrc[idx] : 0;
            int nj = min(64, e - b);
            for (int j = 0; j < nj; ++j) {
                float wk = rdlanef(wv, j);
                int sj = __builtin_amdgcn_readlane(srcn, j);
                acc = fmaf(wk, xl[(size_t)sj * 64 + lane], acc);
            }
        }
    }

    float res = fmaxf(acc + bc[lane], 0.f);

    if (MODE == 0) {
        hout[(size_t)v * 64 + lane] = res;
    } else {
        float part = h1[(size_t)v * 64 + lane] * Wout[lane] + res * Wout[64 + lane];
        #pragma unroll
        for (int off = 32; off; off >>= 1) part += __shfl_xor(part, off);
        if (lane == 0) out[v] = part + bout[0];
    }
}

// ================= launch ===================================================

extern "C" void kernel_launch(void* const* d_in, const int* in_sizes, int n_in,
                              void* d_out, int out_size, void* d_ws, size_t ws_size,
                              hipStream_t stream) {
    const float* x     = (const float*)d_in[0];
    const int*   eidx  = (const int*)d_in[1];
    const float* eattr = (const float*)d_in[2];
    const float* Wl1 = (const float*)d_in[4];
    const float* bl1 = (const float*)d_in[5];
    const float* Wr1 = (const float*)d_in[6];
    const float* br1 = (const float*)d_in[7];
    const float* We1 = (const float*)d_in[8];
    const float* att1 = (const float*)d_in[9];
    const float* bc1 = (const float*)d_in[10];
    const float* Wl2 = (const float*)d_in[11];
    const float* bl2 = (const float*)d_in[12];
    const float* Wr2 = (const float*)d_in[13];
    const float* br2 = (const float*)d_in[14];
    const float* We2 = (const float*)d_in[15];
    const float* att2 = (const float*)d_in[16];
    const float* bc2 = (const float*)d_in[17];
    const float* Wout = (const float*)d_in[18];
    const float* bout = (const float*)d_in[19];

    int N = in_sizes[0] / 64;
    int E = in_sizes[1] / 2;
    int M = E + N;
    const int* srcA = eidx;
    const int* dstA = eidx + E;

    char* w = (char*)d_ws;
    size_t used = 0;
    auto alloc = [&](size_t bytes) {
        char* p = w + used;
        used += (bytes + 255) & ~size_t(255);
        return p;
    };
    int*   cnt    = (int*)alloc((size_t)N * 4);
    int*   fill   = (int*)alloc((size_t)N * 4);
    int*   rowptr = (int*)alloc((size_t)(N + 1) * 4);
    int*   bsum   = (int*)alloc(1024 * 4);
    int*   ssrc   = (int*)alloc((size_t)M * 4);
    int*   sdst   = (int*)alloc((size_t)M * 4);
    int*   seid   = (int*)alloc((size_t)M * 4);
    float* escr   = (float*)alloc((size_t)M * 4);
    float* mattr  = (float*)alloc((size_t)N * 16 * 4);
    float* xl     = (float*)alloc((size_t)N * 64 * 4);
    float* xr     = (float*)alloc((size_t)N * 64 * 4);
    float* h1     = (float*)alloc((size_t)N * 64 * 4);
    size_t eperm_bytes = (size_t)M * 16 * 4;
    bool perm = (used + eperm_bytes) <= ws_size;
    float* eperm = perm ? (float*)alloc(eperm_bytes) : nullptr;

    hipMemsetAsync(cnt, 0, (size_t)N * 4, stream);
    hipMemsetAsync(fill, 0, (size_t)N * 4, stream);
    hipMemsetAsync(seid, 0xFF, (size_t)M * 4, stream);

    int NB = (N + 255) / 256;
    count_k<<<(E + 255) / 256, 256, 0, stream>>>(dstA, cnt, E);
    scan1_k<<<NB, 256, 0, stream>>>(cnt, rowptr, bsum, N);
    scan2_k<<<1, 1024, 0, stream>>>(bsum, NB);
    scan3_k<<<NB, 256, 0, stream>>>(rowptr, bsum, N, M);
    fill_k<<<(E + 255) / 256, 256, 0, stream>>>(srcA, dstA, rowptr, fill,
                                                ssrc, sdst, seid, E);

    if (perm) {
        permute_k<<<(M * 4 + 255) / 256, 256, 0, stream>>>(eattr, seid, eperm, M);
        mean_k<1><<<(N * 16 + 255) / 256, 256, 0, stream>>>(
            eattr, seid, rowptr, eperm, mattr, ssrc, sdst, N);
    } else {
        mean_k<0><<<(N * 16 + 255) / 256, 256, 0, stream>>>(
            eattr, seid, rowptr, nullptr, mattr, ssrc, sdst, N);
    }

    int nodeBlocks = (N + 3) / 4;
    int slotBlocks = (M + 511) / 512;   // 512 slots per block (2 per lane)

    // ---- layer 1
    xfrm_k<<<nodeBlocks, 256, 0, stream>>>(x, Wl1, bl1, Wr1, br1, xl, xr, N);
    if (perm)
        escore_k<1><<<slotBlocks, 256, 0, stream>>>(xl, xr, eperm, eattr, seid, mattr,
                                                    ssrc, sdst, We1, att1, escr, M);
    else
        escore_k<0><<<slotBlocks, 256, 0, stream>>>(xl, xr, nullptr, eattr, seid, mattr,
                                                    ssrc, sdst, We1, att1, escr, M);
    aggregate_k<0><<<nodeBlocks, 256, 0, stream>>>(xl, escr, ssrc, rowptr, bc1, h1,
                                                   nullptr, nullptr, nullptr, nullptr, N);

    // ---- layer 2 (+ fused JK-cat readout)
    xfrm_k<<<nodeBlocks, 256, 0, stream>>>(h1, Wl2, bl2, Wr2, br2, xl, xr, N);
    if (perm)
        escore_k<1><<<slotBlocks, 256, 0, stream>>>(xl, xr, eperm, eattr, seid, mattr,
                                                    ssrc, sdst, We2, att2, escr, M);
    else
        escore_k<0><<<slotBlocks, 256, 0, stream>>>(xl, xr, nullptr, eattr, seid, mattr,
                                                    ssrc, sdst, We2, att2, escr, M);
    aggregate_k<1><<<nodeBlocks, 256, 0, stream>>>(xl, escr, ssrc, rowptr, bc2, nullptr,
                                                   h1, Wout, bout, (float*)d_out, N);
}

// Round 8
// 616.968 us; speedup vs baseline: 1.1538x; 1.1538x over previous
//
#include <hip/hip_runtime.h>

constexpr float NEG_SLOPE = 0.2f;
constexpr float EPS = 1e-16f;
constexpr float NEG_INF = -1e30f;

// ================= CSR build (self-loop slot = LAST slot of each node) ======

__global__ void count_k(const int* __restrict__ dst, int* __restrict__ cnt, int E) {
    int i = blockIdx.x * blockDim.x + threadIdx.x;
    if (i < E) atomicAdd(&cnt[dst[i]], 1);
}

__global__ void scan1_k(const int* __restrict__ in, int* __restrict__ out,
                        int* __restrict__ bsum, int n) {
    __shared__ int s[256];
    int tid = threadIdx.x;
    int i = blockIdx.x * 256 + tid;
    int v = (i < n) ? in[i] + 1 : 0;   // +1 self-loop slot
    s[tid] = v;
    __syncthreads();
    #pragma unroll
    for (int off = 1; off < 256; off <<= 1) {
        int t = (tid >= off) ? s[tid - off] : 0;
        __syncthreads();
        s[tid] += t;
        __syncthreads();
    }
    if (i < n) out[i] = s[tid] - v;
    if (tid == 255) bsum[blockIdx.x] = s[255];
}

__global__ void scan2_k(int* __restrict__ bsum, int nb) {
    __shared__ int s[1024];
    int tid = threadIdx.x;
    int v = (tid < nb) ? bsum[tid] : 0;
    s[tid] = v;
    __syncthreads();
    #pragma unroll
    for (int off = 1; off < 1024; off <<= 1) {
        int t = (tid >= off) ? s[tid - off] : 0;
        __syncthreads();
        s[tid] += t;
        __syncthreads();
    }
    if (tid < nb) bsum[tid] = s[tid] - v;
}

__global__ void scan3_k(int* __restrict__ rowptr, const int* __restrict__ bsum,
                        int n, int M) {
    int i = blockIdx.x * 256 + threadIdx.x;
    if (i < n) rowptr[i] += bsum[blockIdx.x];
    if (i == 0) rowptr[n] = M;
}

__global__ void fill_k(const int* __restrict__ src, const int* __restrict__ dst,
                       const int* __restrict__ rowptr, int* __restrict__ fill,
                       int* __restrict__ ssrc, int* __restrict__ sdst,
                       int* __restrict__ seid, int E) {
    int i = blockIdx.x * blockDim.x + threadIdx.x;
    if (i < E) {
        int d = dst[i];
        int pos = rowptr[d] + atomicAdd(&fill[d], 1);
        ssrc[pos] = src[i];
        sdst[pos] = d;
        seid[pos] = i;        // self slots stay -1 (memset 0xFF)
    }
}

// permute edge_attr into CSR slot order; self slots (seid<0) skipped here,
// filled by mean_k.
__global__ void permute_k(const float* __restrict__ ea, const int* __restrict__ seid,
                          float* __restrict__ eperm, int M) {
    int t = blockIdx.x * blockDim.x + threadIdx.x;   // t = k*4 + c
    if (t >= M * 4) return;
    int k = t >> 2, c = t & 3;
    int eid = seid[k];
    if (eid < 0) return;
    const float4* srcr = reinterpret_cast<const float4*>(ea) + (size_t)eid * 4;
    reinterpret_cast<float4*>(eperm)[(size_t)k * 4 + c] = srcr[c];
}

template <int PERM>
__global__ void mean_k(const float* __restrict__ ea, const int* __restrict__ seid,
                       const int* __restrict__ rowptr,
                       float* __restrict__ eperm, float* __restrict__ mattr,
                       int* __restrict__ ssrc, int* __restrict__ sdst, int N) {
    int t = blockIdx.x * blockDim.x + threadIdx.x;
    if (t >= N * 16) return;
    int v = t >> 4, f = t & 15;
    int s = rowptr[v], sEnd = rowptr[v + 1] - 1;   // real edges in [s, sEnd)
    float sum = 0.f;
    for (int k = s; k < sEnd; k++) {
        size_t row = PERM ? (size_t)k : (size_t)seid[k];
        sum += PERM ? eperm[row * 16 + f] : ea[row * 16 + f];
    }
    int c = sEnd - s;
    float mean = sum / (float)(c > 1 ? c : 1);
    if (PERM) eperm[(size_t)sEnd * 16 + f] = mean;
    else      mattr[(size_t)v * 16 + f] = mean;
    if (f == 0) { ssrc[sEnd] = v; sdst[sEnd] = v; }
}

// ============= node transforms: xl = x@Wl+bl, xr = x@Wr+br ==================
// 8 nodes per wave; weights interleaved as float2 in LDS (one ds_read_b64
// feeds both accumulators); x rows are wave-uniform -> scalar loads.

__global__ __launch_bounds__(256) void xfrm_k(
        const float* __restrict__ x,
        const float* __restrict__ Wl, const float* __restrict__ bl,
        const float* __restrict__ Wr, const float* __restrict__ br,
        float* __restrict__ xl, float* __restrict__ xr, int N) {
    __shared__ float2 sW[64 * 64];   // sW[d*64+h] = (Wl[d][h], Wr[d][h])
    for (int i = threadIdx.x; i < 64 * 64; i += 256)
        sW[i] = make_float2(Wl[i], Wr[i]);
    __syncthreads();

    int lane = threadIdx.x & 63;
    int base = __builtin_amdgcn_readfirstlane(
        (blockIdx.x * 4 + (threadIdx.x >> 6)) * 8);
    if (base >= N) return;

    const float4* xb = reinterpret_cast<const float4*>(x);
    int r[8];
    #pragma unroll
    for (int n = 0; n < 8; ++n) r[n] = min(base + n, N - 1) * 16;

    float blh = bl[lane], brh = br[lane];
    float2 acc[8];
    #pragma unroll
    for (int n = 0; n < 8; ++n) acc[n] = make_float2(blh, brh);

    #pragma unroll 4
    for (int d4 = 0; d4 < 16; ++d4) {
        float4 xv[8];
        #pragma unroll
        for (int n = 0; n < 8; ++n) xv[n] = xb[r[n] + d4];
        #pragma unroll
        for (int j = 0; j < 4; ++j) {
            float2 wp = sW[(d4 * 4 + j) * 64 + lane];
            #pragma unroll
            for (int n = 0; n < 8; ++n) {
                float xs = (j == 0) ? xv[n].x : (j == 1) ? xv[n].y
                         : (j == 2) ? xv[n].z : xv[n].w;
                acc[n].x = fmaf(xs, wp.x, acc[n].x);
                acc[n].y = fmaf(xs, wp.y, acc[n].y);
            }
        }
    }

    #pragma unroll
    for (int n = 0; n < 8; ++n) {
        int v = base + n;
        if (v < N) {
            xl[(size_t)v * 64 + lane] = acc[n].x;
            xr[(size_t)v * 64 + lane] = acc[n].y;
        }
    }
}

// ================= Pass A: per-slot scores, LANE = EDGE =====================
// Each lane owns 2 slots; reduction over the 64 features happens in a scalar
// register accumulator — no cross-lane ops at all. We/att broadcast from LDS.

template <int PERM>
__global__ __launch_bounds__(256) void escore_k(
        const float* __restrict__ xl, const float* __restrict__ xr,
        const float* __restrict__ eperm,   // CSR-ordered attrs (PERM=1)
        const float* __restrict__ earaw, const int* __restrict__ seid,
        const float* __restrict__ mattr,
        const int* __restrict__ ssrc, const int* __restrict__ sdst,
        const float* __restrict__ We, const float* __restrict__ att,
        float* __restrict__ escr, int M) {
    __shared__ float4 sWe[16 * 16];   // [d][j] = We[d][4j..4j+3]
    __shared__ float4 sAtt[16];
    int tid = threadIdx.x;
    {
        const float4* We4 = reinterpret_cast<const float4*>(We);
        if (tid < 256) sWe[tid] = We4[tid];
        if (tid < 16) sAtt[tid] = reinterpret_cast<const float4*>(att)[tid];
    }
    __syncthreads();

    int lane = tid & 63;
    int base = (blockIdx.x * 4 + (tid >> 6)) * 128;
    if (base >= M) return;
    int k0 = base + lane;
    int k1 = k0 + 64;
    int k0c = min(k0, M - 1);
    int k1c = min(k1, M - 1);

    int s0 = ssrc[k0c], d0 = sdst[k0c];
    int s1 = ssrc[k1c], d1 = sdst[k1c];

    const float4* rp0;
    const float4* rp1;
    if (PERM) {
        rp0 = reinterpret_cast<const float4*>(eperm) + (size_t)k0c * 4;
        rp1 = reinterpret_cast<const float4*>(eperm) + (size_t)k1c * 4;
    } else {
        int e0 = seid[k0c], e1 = seid[k1c];
        rp0 = (e0 < 0) ? reinterpret_cast<const float4*>(mattr) + (size_t)d0 * 4
                       : reinterpret_cast<const float4*>(earaw) + (size_t)e0 * 4;
        rp1 = (e1 < 0) ? reinterpret_cast<const float4*>(mattr) + (size_t)d1 * 4
                       : reinterpret_cast<const float4*>(earaw) + (size_t)e1 * 4;
    }

    float ea0[16], ea1[16];
    #pragma unroll
    for (int q = 0; q < 4; q++) {
        float4 a = rp0[q];
        ea0[q * 4 + 0] = a.x; ea0[q * 4 + 1] = a.y;
        ea0[q * 4 + 2] = a.z; ea0[q * 4 + 3] = a.w;
        float4 b = rp1[q];
        ea1[q * 4 + 0] = b.x; ea1[q * 4 + 1] = b.y;
        ea1[q * 4 + 2] = b.z; ea1[q * 4 + 3] = b.w;
    }

    const float4* xl4 = reinterpret_cast<const float4*>(xl);
    const float4* xr4 = reinterpret_cast<const float4*>(xr);
    size_t xs0 = (size_t)s0 * 16, xd0 = (size_t)d0 * 16;
    size_t xs1 = (size_t)s1 * 16, xd1 = (size_t)d1 * 16;

    float acc0 = 0.f, acc1 = 0.f;
    #pragma unroll 4
    for (int j = 0; j < 16; ++j) {
        float4 x0 = xl4[xs0 + j];
        float4 r0 = xr4[xd0 + j];
        float4 x1 = xl4[xs1 + j];
        float4 r1 = xr4[xd1 + j];
        float4 ee0 = {0.f, 0.f, 0.f, 0.f};
        float4 ee1 = {0.f, 0.f, 0.f, 0.f};
        #pragma unroll
        for (int d = 0; d < 16; ++d) {
            float4 w = sWe[d * 16 + j];
            float a0 = ea0[d], a1 = ea1[d];
            ee0.x = fmaf(a0, w.x, ee0.x);
            ee0.y = fmaf(a0, w.y, ee0.y);
            ee0.z = fmaf(a0, w.z, ee0.z);
            ee0.w = fmaf(a0, w.w, ee0.w);
            ee1.x = fmaf(a1, w.x, ee1.x);
            ee1.y = fmaf(a1, w.y, ee1.y);
            ee1.z = fmaf(a1, w.z, ee1.z);
            ee1.w = fmaf(a1, w.w, ee1.w);
        }
        float4 a4 = sAtt[j];
        float m;
        m = x0.x + r0.x + ee0.x; m = (m > 0.f) ? m : NEG_SLOPE * m; acc0 = fmaf(a4.x, m, acc0);
        m = x0.y + r0.y + ee0.y; m = (m > 0.f) ? m : NEG_SLOPE * m; acc0 = fmaf(a4.y, m, acc0);
        m = x0.z + r0.z + ee0.z; m = (m > 0.f) ? m : NEG_SLOPE * m; acc0 = fmaf(a4.z, m, acc0);
        m = x0.w + r0.w + ee0.w; m = (m > 0.f) ? m : NEG_SLOPE * m; acc0 = fmaf(a4.w, m, acc0);
        m = x1.x + r1.x + ee1.x; m = (m > 0.f) ? m : NEG_SLOPE * m; acc1 = fmaf(a4.x, m, acc1);
        m = x1.y + r1.y + ee1.y; m = (m > 0.f) ? m : NEG_SLOPE * m; acc1 = fmaf(a4.y, m, acc1);
        m = x1.z + r1.z + ee1.z; m = (m > 0.f) ? m : NEG_SLOPE * m; acc1 = fmaf(a4.z, m, acc1);
        m = x1.w + r1.w + ee1.w; m = (m > 0.f) ? m : NEG_SLOPE * m; acc1 = fmaf(a4.w, m, acc1);
    }
    if (k0 < M) escr[k0] = acc0;
    if (k1 < M) escr[k1] = acc1;
}

// ================= Pass B: softmax + weighted aggregation ===================

__device__ __forceinline__ float rdlanef(float x, int j) {
    return __int_as_float(__builtin_amdgcn_readlane(__float_as_int(x), j));
}

template <int MODE>
__global__ __launch_bounds__(256) void aggregate_k(
        const float* __restrict__ xl, const float* __restrict__ escr,
        const int* __restrict__ ssrc, const int* __restrict__ rowptr,
        const float* __restrict__ bc,
        float* __restrict__ hout,
        const float* __restrict__ h1, const float* __restrict__ Wout,
        const float* __restrict__ bout, float* __restrict__ out, int N) {
    int lane = threadIdx.x & 63;
    int v = blockIdx.x * 4 + (threadIdx.x >> 6);
    if (v >= N) return;

    int s = rowptr[v], e = rowptr[v + 1];
    int deg = e - s;
    float acc;

    if (deg <= 64) {
        // ---- fast path: all scores fit one wave
        int idx = s + lane;
        bool valid = lane < deg;
        float sc = valid ? escr[idx] : NEG_INF;
        float m = sc;
        #pragma unroll
        for (int off = 32; off; off >>= 1) m = fmaxf(m, __shfl_xor(m, off));
        float t = valid ? __expf(sc - m) : 0.f;
        float dsum = t;
        #pragma unroll
        for (int off = 32; off; off >>= 1) dsum += __shfl_xor(dsum, off);
        float alpha = t / (dsum + EPS);
        int srcn = valid ? ssrc[idx] : 0;

        float a0 = 0.f, a1 = 0.f, a2 = 0.f, a3 = 0.f;
        int j = 0;
        for (; j + 4 <= deg; j += 4) {
            int sj0 = __builtin_amdgcn_readlane(srcn, j);
            int sj1 = __builtin_amdgcn_readlane(srcn, j + 1);
            int sj2 = __builtin_amdgcn_readlane(srcn, j + 2);
            int sj3 = __builtin_amdgcn_readlane(srcn, j + 3);
            float w0 = rdlanef(alpha, j);
            float w1 = rdlanef(alpha, j + 1);
            float w2 = rdlanef(alpha, j + 2);
            float w3 = rdlanef(alpha, j + 3);
            a0 = fmaf(w0, xl[(size_t)sj0 * 64 + lane], a0);
            a1 = fmaf(w1, xl[(size_t)sj1 * 64 + lane], a1);
            a2 = fmaf(w2, xl[(size_t)sj2 * 64 + lane], a2);
            a3 = fmaf(w3, xl[(size_t)sj3 * 64 + lane], a3);
        }
        for (; j < deg; ++j) {
            int sj = __builtin_amdgcn_readlane(srcn, j);
            float wj = rdlanef(alpha, j);
            a0 = fmaf(wj, xl[(size_t)sj * 64 + lane], a0);
        }
        acc = (a0 + a1) + (a2 + a3);
    } else {
        // ---- general path (rare): chunked
        float m = NEG_INF;
        for (int b = s; b < e; b += 64) {
            int idx = b + lane;
            float val = (idx < e) ? escr[idx] : NEG_INF;
            #pragma unroll
            for (int off = 32; off; off >>= 1) val = fmaxf(val, __shfl_xor(val, off));
            m = fmaxf(m, val);
        }
        float denom = 0.f;
        for (int b = s; b < e; b += 64) {
            int idx = b + lane;
            float t = (idx < e) ? __expf(escr[idx] - m) : 0.f;
            #pragma unroll
            for (int off = 32; off; off >>= 1) t += __shfl_xor(t, off);
            denom += t;
        }
        float inv = 1.f / (denom + EPS);
        acc = 0.f;
        for (int b = s; b < e; b += 64) {
            int idx = b + lane;
            float wv = (idx < e) ? __expf(escr[idx] - m) * inv : 0.f;
            int srcn = (idx < e) ? ssrc[idx] : 0;
            int nj = min(64, e - b);
            for (int j = 0; j < nj; ++j) {
                float wk = rdlanef(wv, j);
                int sj = __builtin_amdgcn_readlane(srcn, j);
                acc = fmaf(wk, xl[(size_t)sj * 64 + lane], acc);
            }
        }
    }

    float res = fmaxf(acc + bc[lane], 0.f);

    if (MODE == 0) {
        hout[(size_t)v * 64 + lane] = res;
    } else {
        float part = h1[(size_t)v * 64 + lane] * Wout[lane] + res * Wout[64 + lane];
        #pragma unroll
        for (int off = 32; off; off >>= 1) part += __shfl_xor(part, off);
        if (lane == 0) out[v] = part + bout[0];
    }
}

// ================= launch ===================================================

extern "C" void kernel_launch(void* const* d_in, const int* in_sizes, int n_in,
                              void* d_out, int out_size, void* d_ws, size_t ws_size,
                              hipStream_t stream) {
    const float* x     = (const float*)d_in[0];
    const int*   eidx  = (const int*)d_in[1];
    const float* eattr = (const float*)d_in[2];
    const float* Wl1 = (const float*)d_in[4];
    const float* bl1 = (const float*)d_in[5];
    const float* Wr1 = (const float*)d_in[6];
    const float* br1 = (const float*)d_in[7];
    const float* We1 = (const float*)d_in[8];
    const float* att1 = (const float*)d_in[9];
    const float* bc1 = (const float*)d_in[10];
    const float* Wl2 = (const float*)d_in[11];
    const float* bl2 = (const float*)d_in[12];
    const float* Wr2 = (const float*)d_in[13];
    const float* br2 = (const float*)d_in[14];
    const float* We2 = (const float*)d_in[15];
    const float* att2 = (const float*)d_in[16];
    const float* bc2 = (const float*)d_in[17];
    const float* Wout = (const float*)d_in[18];
    const float* bout = (const float*)d_in[19];

    int N = in_sizes[0] / 64;
    int E = in_sizes[1] / 2;
    int M = E + N;
    const int* srcA = eidx;
    const int* dstA = eidx + E;

    char* w = (char*)d_ws;
    size_t used = 0;
    auto alloc = [&](size_t bytes) {
        char* p = w + used;
        used += (bytes + 255) & ~size_t(255);
        return p;
    };
    int*   cnt    = (int*)alloc((size_t)N * 4);
    int*   fill   = (int*)alloc((size_t)N * 4);
    int*   rowptr = (int*)alloc((size_t)(N + 1) * 4);
    int*   bsum   = (int*)alloc(1024 * 4);
    int*   ssrc   = (int*)alloc((size_t)M * 4);
    int*   sdst   = (int*)alloc((size_t)M * 4);
    int*   seid   = (int*)alloc((size_t)M * 4);
    float* escr   = (float*)alloc((size_t)M * 4);
    float* mattr  = (float*)alloc((size_t)N * 16 * 4);
    float* xl     = (float*)alloc((size_t)N * 64 * 4);
    float* xr     = (float*)alloc((size_t)N * 64 * 4);
    float* h1     = (float*)alloc((size_t)N * 64 * 4);
    size_t eperm_bytes = (size_t)M * 16 * 4;
    bool perm = (used + eperm_bytes) <= ws_size;
    float* eperm = perm ? (float*)alloc(eperm_bytes) : nullptr;

    hipMemsetAsync(cnt, 0, (size_t)N * 4, stream);
    hipMemsetAsync(fill, 0, (size_t)N * 4, stream);
    hipMemsetAsync(seid, 0xFF, (size_t)M * 4, stream);

    int NB = (N + 255) / 256;
    count_k<<<(E + 255) / 256, 256, 0, stream>>>(dstA, cnt, E);
    scan1_k<<<NB, 256, 0, stream>>>(cnt, rowptr, bsum, N);
    scan2_k<<<1, 1024, 0, stream>>>(bsum, NB);
    scan3_k<<<NB, 256, 0, stream>>>(rowptr, bsum, N, M);
    fill_k<<<(E + 255) / 256, 256, 0, stream>>>(srcA, dstA, rowptr, fill,
                                                ssrc, sdst, seid, E);

    if (perm) {
        permute_k<<<(M * 4 + 255) / 256, 256, 0, stream>>>(eattr, seid, eperm, M);
        mean_k<1><<<(N * 16 + 255) / 256, 256, 0, stream>>>(
            eattr, seid, rowptr, eperm, mattr, ssrc, sdst, N);
    } else {
        mean_k<0><<<(N * 16 + 255) / 256, 256, 0, stream>>>(
            eattr, seid, rowptr, nullptr, mattr, ssrc, sdst, N);
    }

    int nodeBlocks = (N + 3) / 4;
    int xfrmBlocks = (N + 31) / 32;     // 32 nodes per block (8 per wave)
    int slotBlocks = (M + 511) / 512;   // 512 slots per block (2 per lane)

    // ---- layer 1
    xfrm_k<<<xfrmBlocks, 256, 0, stream>>>(x, Wl1, bl1, Wr1, br1, xl, xr, N);
    if (perm)
        escore_k<1><<<slotBlocks, 256, 0, stream>>>(xl, xr, eperm, eattr, seid, mattr,
                                                    ssrc, sdst, We1, att1, escr, M);
    else
        escore_k<0><<<slotBlocks, 256, 0, stream>>>(xl, xr, nullptr, eattr, seid, mattr,
                                                    ssrc, sdst, We1, att1, escr, M);
    aggregate_k<0><<<nodeBlocks, 256, 0, stream>>>(xl, escr, ssrc, rowptr, bc1, h1,
                                                   nullptr, nullptr, nullptr, nullptr, N);

    // ---- layer 2 (+ fused JK-cat readout)
    xfrm_k<<<xfrmBlocks, 256, 0, stream>>>(h1, Wl2, bl2, Wr2, br2, xl, xr, N);
    if (perm)
        escore_k<1><<<slotBlocks, 256, 0, stream>>>(xl, xr, eperm, eattr, seid, mattr,
                                                    ssrc, sdst, We2, att2, escr, M);
    else
        escore_k<0><<<slotBlocks, 256, 0, stream>>>(xl, xr, nullptr, eattr, seid, mattr,
                                                    ssrc, sdst, We2, att2, escr, M);
    aggregate_k<1><<<nodeBlocks, 256, 0, stream>>>(xl, escr, ssrc, rowptr, bc2, nullptr,
                                                   h1, Wout, bout, (float*)d_out, N);
}

// Round 9
// 495.345 us; speedup vs baseline: 1.4371x; 1.2455x over previous
//
#include <hip/hip_runtime.h>

constexpr float NEG_SLOPE = 0.2f;
constexpr float EPS = 1e-16f;
constexpr float NEG_INF = -1e30f;

// ---------------- bf16 helpers (manual, RNE) ----------------
__device__ __forceinline__ unsigned short f2bf(float x) {
    unsigned u = __float_as_uint(x);
    u += 0x7FFF + ((u >> 16) & 1);
    return (unsigned short)(u >> 16);
}
__device__ __forceinline__ float bflo(unsigned u) {
    return __uint_as_float(u << 16);
}
__device__ __forceinline__ float bfhi(unsigned u) {
    return __uint_as_float(u & 0xFFFF0000u);
}
__device__ __forceinline__ unsigned packbf(float a, float b) {
    return (unsigned)f2bf(a) | ((unsigned)f2bf(b) << 16);
}
__device__ __forceinline__ void unpack8(uint4 u, float* o) {
    o[0] = bflo(u.x); o[1] = bfhi(u.x);
    o[2] = bflo(u.y); o[3] = bfhi(u.y);
    o[4] = bflo(u.z); o[5] = bfhi(u.z);
    o[6] = bflo(u.w); o[7] = bfhi(u.w);
}

// ================= CSR build (self-loop slot = LAST slot of each node) ======

__global__ void count_k(const int* __restrict__ dst, int* __restrict__ cnt, int E) {
    int i = blockIdx.x * blockDim.x + threadIdx.x;
    if (i < E) atomicAdd(&cnt[dst[i]], 1);
}

__global__ void scan1_k(const int* __restrict__ in, int* __restrict__ out,
                        int* __restrict__ bsum, int n) {
    __shared__ int s[256];
    int tid = threadIdx.x;
    int i = blockIdx.x * 256 + tid;
    int v = (i < n) ? in[i] + 1 : 0;   // +1 self-loop slot
    s[tid] = v;
    __syncthreads();
    #pragma unroll
    for (int off = 1; off < 256; off <<= 1) {
        int t = (tid >= off) ? s[tid - off] : 0;
        __syncthreads();
        s[tid] += t;
        __syncthreads();
    }
    if (i < n) out[i] = s[tid] - v;
    if (tid == 255) bsum[blockIdx.x] = s[255];
}

__global__ void scan2_k(int* __restrict__ bsum, int nb) {
    __shared__ int s[1024];
    int tid = threadIdx.x;
    int v = (tid < nb) ? bsum[tid] : 0;
    s[tid] = v;
    __syncthreads();
    #pragma unroll
    for (int off = 1; off < 1024; off <<= 1) {
        int t = (tid >= off) ? s[tid - off] : 0;
        __syncthreads();
        s[tid] += t;
        __syncthreads();
    }
    if (tid < nb) bsum[tid] = s[tid] - v;
}

__global__ void scan3_k(int* __restrict__ rowptr, const int* __restrict__ bsum,
                        int n, int M) {
    int i = blockIdx.x * 256 + threadIdx.x;
    if (i < n) rowptr[i] += bsum[blockIdx.x];
    if (i == 0) rowptr[n] = M;
}

__global__ void fill_k(const int* __restrict__ src, const int* __restrict__ dst,
                       const int* __restrict__ rowptr, int* __restrict__ fill,
                       int* __restrict__ ssrc, int* __restrict__ sdst,
                       int* __restrict__ seid, int E) {
    int i = blockIdx.x * blockDim.x + threadIdx.x;
    if (i < E) {
        int d = dst[i];
        int pos = rowptr[d] + atomicAdd(&fill[d], 1);
        ssrc[pos] = src[i];
        sdst[pos] = d;
        seid[pos] = i;        // self slots stay -1 (memset 0xFF)
    }
}

// permute edge_attr into CSR slot order AND convert to bf16 (32 B/row).
// self slots (seid<0) skipped here, filled by mean_k.
__global__ void permute_k(const float* __restrict__ ea, const int* __restrict__ seid,
                          unsigned short* __restrict__ eperm_b, int M) {
    int t = blockIdx.x * blockDim.x + threadIdx.x;   // t = k*2 + c (8 floats each)
    if (t >= M * 2) return;
    int k = t >> 1, c = t & 1;
    int eid = seid[k];
    if (eid < 0) return;
    const float4* s4 = reinterpret_cast<const float4*>(ea) + (size_t)eid * 4 + c * 2;
    float4 a = s4[0], b = s4[1];
    uint4 o;
    o.x = packbf(a.x, a.y);
    o.y = packbf(a.z, a.w);
    o.z = packbf(b.x, b.y);
    o.w = packbf(b.z, b.w);
    reinterpret_cast<uint4*>(eperm_b)[(size_t)k * 2 + c] = o;
}

// mean incoming edge_attr; PERM=1 reads bf16 eperm, writes bf16 mean into the
// self-loop row; PERM=0 writes fp32 mattr. Also fills ssrc/sdst self slots.
template <int PERM>
__global__ void mean_k(const float* __restrict__ ea, const int* __restrict__ seid,
                       const int* __restrict__ rowptr,
                       unsigned short* __restrict__ eperm_b, float* __restrict__ mattr,
                       int* __restrict__ ssrc, int* __restrict__ sdst, int N) {
    int t = blockIdx.x * blockDim.x + threadIdx.x;
    if (t >= N * 16) return;
    int v = t >> 4, f = t & 15;
    int s = rowptr[v], sEnd = rowptr[v + 1] - 1;   // real edges in [s, sEnd)
    float sum = 0.f;
    for (int k = s; k < sEnd; k++) {
        if (PERM) sum += bflo((unsigned)eperm_b[(size_t)k * 16 + f]);
        else      sum += ea[(size_t)seid[k] * 16 + f];
    }
    int c = sEnd - s;
    float mean = sum / (float)(c > 1 ? c : 1);
    if (PERM) eperm_b[(size_t)sEnd * 16 + f] = f2bf(mean);
    else      mattr[(size_t)v * 16 + f] = mean;
    if (f == 0) { ssrc[sEnd] = v; sdst[sEnd] = v; }
}

// ============= node transforms: xl = x@Wl+bl, xr = x@Wr+br (bf16 out) =======
// 8 nodes per wave; weights interleaved as float2 in LDS.

__global__ __launch_bounds__(256) void xfrm_k(
        const float* __restrict__ x,
        const float* __restrict__ Wl, const float* __restrict__ bl,
        const float* __restrict__ Wr, const float* __restrict__ br,
        unsigned short* __restrict__ xl_b, unsigned short* __restrict__ xr_b, int N) {
    __shared__ float2 sW[64 * 64];   // sW[d*64+h] = (Wl[d][h], Wr[d][h])
    for (int i = threadIdx.x; i < 64 * 64; i += 256)
        sW[i] = make_float2(Wl[i], Wr[i]);
    __syncthreads();

    int lane = threadIdx.x & 63;
    int base = __builtin_amdgcn_readfirstlane(
        (blockIdx.x * 4 + (threadIdx.x >> 6)) * 8);
    if (base >= N) return;

    const float4* xb = reinterpret_cast<const float4*>(x);
    int r[8];
    #pragma unroll
    for (int n = 0; n < 8; ++n) r[n] = min(base + n, N - 1) * 16;

    float blh = bl[lane], brh = br[lane];
    float2 acc[8];
    #pragma unroll
    for (int n = 0; n < 8; ++n) acc[n] = make_float2(blh, brh);

    #pragma unroll 4
    for (int d4 = 0; d4 < 16; ++d4) {
        float4 xv[8];
        #pragma unroll
        for (int n = 0; n < 8; ++n) xv[n] = xb[r[n] + d4];
        #pragma unroll
        for (int j = 0; j < 4; ++j) {
            float2 wp = sW[(d4 * 4 + j) * 64 + lane];
            #pragma unroll
            for (int n = 0; n < 8; ++n) {
                float xs = (j == 0) ? xv[n].x : (j == 1) ? xv[n].y
                         : (j == 2) ? xv[n].z : xv[n].w;
                acc[n].x = fmaf(xs, wp.x, acc[n].x);
                acc[n].y = fmaf(xs, wp.y, acc[n].y);
            }
        }
    }

    #pragma unroll
    for (int n = 0; n < 8; ++n) {
        int v = base + n;
        if (v < N) {
            xl_b[(size_t)v * 64 + lane] = f2bf(acc[n].x);
            xr_b[(size_t)v * 64 + lane] = f2bf(acc[n].y);
        }
    }
}

// ================= Pass A: per-slot scores, LANE = EDGE =====================
// Each lane owns 2 slots; per-slot reduction in a scalar register. bf16 rows.

template <int PERM>
__global__ __launch_bounds__(256) void escore_k(
        const unsigned short* __restrict__ xl_b, const unsigned short* __restrict__ xr_b,
        const unsigned short* __restrict__ eperm_b,   // bf16 CSR-ordered attrs
        const float* __restrict__ earaw, const int* __restrict__ seid,
        const float* __restrict__ mattr,
        const int* __restrict__ ssrc, const int* __restrict__ sdst,
        const float* __restrict__ We, const float* __restrict__ att,
        float* __restrict__ escr, int M) {
    __shared__ float4 sWe[16 * 16];   // [d][j] = We[d][4j..4j+3]
    __shared__ float4 sAtt[16];
    int tid = threadIdx.x;
    {
        const float4* We4 = reinterpret_cast<const float4*>(We);
        if (tid < 256) sWe[tid] = We4[tid];
        if (tid < 16) sAtt[tid] = reinterpret_cast<const float4*>(att)[tid];
    }
    __syncthreads();

    int lane = tid & 63;
    int base = (blockIdx.x * 4 + (tid >> 6)) * 128;
    if (base >= M) return;
    int k0 = base + lane;
    int k1 = k0 + 64;
    int k0c = min(k0, M - 1);
    int k1c = min(k1, M - 1);

    int s0 = ssrc[k0c], d0 = sdst[k0c];
    int s1 = ssrc[k1c], d1 = sdst[k1c];

    float ea0[16], ea1[16];
    if (PERM) {
        const uint4* ep4 = reinterpret_cast<const uint4*>(eperm_b);
        uint4 a0 = ep4[(size_t)k0c * 2], a1 = ep4[(size_t)k0c * 2 + 1];
        uint4 b0 = ep4[(size_t)k1c * 2], b1 = ep4[(size_t)k1c * 2 + 1];
        unpack8(a0, ea0); unpack8(a1, ea0 + 8);
        unpack8(b0, ea1); unpack8(b1, ea1 + 8);
    } else {
        int e0 = seid[k0c], e1 = seid[k1c];
        const float4* rp0 = (e0 < 0)
            ? reinterpret_cast<const float4*>(mattr) + (size_t)d0 * 4
            : reinterpret_cast<const float4*>(earaw) + (size_t)e0 * 4;
        const float4* rp1 = (e1 < 0)
            ? reinterpret_cast<const float4*>(mattr) + (size_t)d1 * 4
            : reinterpret_cast<const float4*>(earaw) + (size_t)e1 * 4;
        #pragma unroll
        for (int q = 0; q < 4; q++) {
            float4 a = rp0[q];
            ea0[q * 4 + 0] = a.x; ea0[q * 4 + 1] = a.y;
            ea0[q * 4 + 2] = a.z; ea0[q * 4 + 3] = a.w;
            float4 b = rp1[q];
            ea1[q * 4 + 0] = b.x; ea1[q * 4 + 1] = b.y;
            ea1[q * 4 + 2] = b.z; ea1[q * 4 + 3] = b.w;
        }
    }

    const uint2* xl2 = reinterpret_cast<const uint2*>(xl_b);   // 4 bf16 per uint2
    const uint2* xr2 = reinterpret_cast<const uint2*>(xr_b);
    size_t xs0 = (size_t)s0 * 16, xd0 = (size_t)d0 * 16;
    size_t xs1 = (size_t)s1 * 16, xd1 = (size_t)d1 * 16;

    float acc0 = 0.f, acc1 = 0.f;
    #pragma unroll 4
    for (int j = 0; j < 16; ++j) {
        uint2 ux0 = xl2[xs0 + j];
        uint2 ur0 = xr2[xd0 + j];
        uint2 ux1 = xl2[xs1 + j];
        uint2 ur1 = xr2[xd1 + j];
        float4 ee0 = {0.f, 0.f, 0.f, 0.f};
        float4 ee1 = {0.f, 0.f, 0.f, 0.f};
        #pragma unroll
        for (int d = 0; d < 16; ++d) {
            float4 w = sWe[d * 16 + j];
            float a0 = ea0[d], a1 = ea1[d];
            ee0.x = fmaf(a0, w.x, ee0.x);
            ee0.y = fmaf(a0, w.y, ee0.y);
            ee0.z = fmaf(a0, w.z, ee0.z);
            ee0.w = fmaf(a0, w.w, ee0.w);
            ee1.x = fmaf(a1, w.x, ee1.x);
            ee1.y = fmaf(a1, w.y, ee1.y);
            ee1.z = fmaf(a1, w.z, ee1.z);
            ee1.w = fmaf(a1, w.w, ee1.w);
        }
        float4 a4 = sAtt[j];
        float m;
        m = bflo(ux0.x) + bflo(ur0.x) + ee0.x; m = (m > 0.f) ? m : NEG_SLOPE * m; acc0 = fmaf(a4.x, m, acc0);
        m = bfhi(ux0.x) + bfhi(ur0.x) + ee0.y; m = (m > 0.f) ? m : NEG_SLOPE * m; acc0 = fmaf(a4.y, m, acc0);
        m = bflo(ux0.y) + bflo(ur0.y) + ee0.z; m = (m > 0.f) ? m : NEG_SLOPE * m; acc0 = fmaf(a4.z, m, acc0);
        m = bfhi(ux0.y) + bfhi(ur0.y) + ee0.w; m = (m > 0.f) ? m : NEG_SLOPE * m; acc0 = fmaf(a4.w, m, acc0);
        m = bflo(ux1.x) + bflo(ur1.x) + ee1.x; m = (m > 0.f) ? m : NEG_SLOPE * m; acc1 = fmaf(a4.x, m, acc1);
        m = bfhi(ux1.x) + bfhi(ur1.x) + ee1.y; m = (m > 0.f) ? m : NEG_SLOPE * m; acc1 = fmaf(a4.y, m, acc1);
        m = bflo(ux1.y) + bflo(ur1.y) + ee1.z; m = (m > 0.f) ? m : NEG_SLOPE * m; acc1 = fmaf(a4.z, m, acc1);
        m = bfhi(ux1.y) + bfhi(ur1.y) + ee1.w; m = (m > 0.f) ? m : NEG_SLOPE * m; acc1 = fmaf(a4.w, m, acc1);
    }
    if (k0 < M) escr[k0] = acc0;
    if (k1 < M) escr[k1] = acc1;
}

// ================= Pass B: softmax + weighted aggregation ===================

__device__ __forceinline__ float rdlanef(float x, int j) {
    return __int_as_float(__builtin_amdgcn_readlane(__float_as_int(x), j));
}

template <int MODE>
__global__ __launch_bounds__(256) void aggregate_k(
        const unsigned short* __restrict__ xl_b, const float* __restrict__ escr,
        const int* __restrict__ ssrc, const int* __restrict__ rowptr,
        const float* __restrict__ bc,
        float* __restrict__ hout,
        const float* __restrict__ h1, const float* __restrict__ Wout,
        const float* __restrict__ bout, float* __restrict__ out, int N) {
    int lane = threadIdx.x & 63;
    int v = blockIdx.x * 4 + (threadIdx.x >> 6);
    if (v >= N) return;

    int s = rowptr[v], e = rowptr[v + 1];
    int deg = e - s;
    float acc;

    if (deg <= 64) {
        // ---- fast path: all scores fit one wave
        int idx = s + lane;
        bool valid = lane < deg;
        float sc = valid ? escr[idx] : NEG_INF;
        float m = sc;
        #pragma unroll
        for (int off = 32; off; off >>= 1) m = fmaxf(m, __shfl_xor(m, off));
        float t = valid ? __expf(sc - m) : 0.f;
        float dsum = t;
        #pragma unroll
        for (int off = 32; off; off >>= 1) dsum += __shfl_xor(dsum, off);
        float alpha = t / (dsum + EPS);
        int srcn = valid ? ssrc[idx] : 0;

        float a0 = 0.f, a1 = 0.f, a2 = 0.f, a3 = 0.f;
        int j = 0;
        for (; j + 4 <= deg; j += 4) {
            int sj0 = __builtin_amdgcn_readlane(srcn, j);
            int sj1 = __builtin_amdgcn_readlane(srcn, j + 1);
            int sj2 = __builtin_amdgcn_readlane(srcn, j + 2);
            int sj3 = __builtin_amdgcn_readlane(srcn, j + 3);
            float w0 = rdlanef(alpha, j);
            float w1 = rdlanef(alpha, j + 1);
            float w2 = rdlanef(alpha, j + 2);
            float w3 = rdlanef(alpha, j + 3);
            a0 = fmaf(w0, bflo((unsigned)xl_b[(size_t)sj0 * 64 + lane]), a0);
            a1 = fmaf(w1, bflo((unsigned)xl_b[(size_t)sj1 * 64 + lane]), a1);
            a2 = fmaf(w2, bflo((unsigned)xl_b[(size_t)sj2 * 64 + lane]), a2);
            a3 = fmaf(w3, bflo((unsigned)xl_b[(size_t)sj3 * 64 + lane]), a3);
        }
        for (; j < deg; ++j) {
            int sj = __builtin_amdgcn_readlane(srcn, j);
            float wj = rdlanef(alpha, j);
            a0 = fmaf(wj, bflo((unsigned)xl_b[(size_t)sj * 64 + lane]), a0);
        }
        acc = (a0 + a1) + (a2 + a3);
    } else {
        // ---- general path (rare): chunked
        float m = NEG_INF;
        for (int b = s; b < e; b += 64) {
            int idx = b + lane;
            float val = (idx < e) ? escr[idx] : NEG_INF;
            #pragma unroll
            for (int off = 32; off; off >>= 1) val = fmaxf(val, __shfl_xor(val, off));
            m = fmaxf(m, val);
        }
        float denom = 0.f;
        for (int b = s; b < e; b += 64) {
            int idx = b + lane;
            float t = (idx < e) ? __expf(escr[idx] - m) : 0.f;
            #pragma unroll
            for (int off = 32; off; off >>= 1) t += __shfl_xor(t, off);
            denom += t;
        }
        float inv = 1.f / (denom + EPS);
        acc = 0.f;
        for (int b = s; b < e; b += 64) {
            int idx = b + lane;
            float wv = (idx < e) ? __expf(escr[idx] - m) * inv : 0.f;
            int srcn = (idx < e) ? ssrc[idx] : 0;
            int nj = min(64, e - b);
            for (int j = 0; j < nj; ++j) {
                float wk = rdlanef(wv, j);
                int sj = __builtin_amdgcn_readlane(srcn, j);
                acc = fmaf(wk, bflo((unsigned)xl_b[(size_t)sj * 64 + lane]), acc);
            }
        }
    }

    float res = fmaxf(acc + bc[lane], 0.f);

    if (MODE == 0) {
        hout[(size_t)v * 64 + lane] = res;
    } else {
        float part = h1[(size_t)v * 64 + lane] * Wout[lane] + res * Wout[64 + lane];
        #pragma unroll
        for (int off = 32; off; off >>= 1) part += __shfl_xor(part, off);
        if (lane == 0) out[v] = part + bout[0];
    }
}

// ================= launch ===================================================

extern "C" void kernel_launch(void* const* d_in, const int* in_sizes, int n_in,
                              void* d_out, int out_size, void* d_ws, size_t ws_size,
                              hipStream_t stream) {
    const float* x     = (const float*)d_in[0];
    const int*   eidx  = (const int*)d_in[1];
    const float* eattr = (const float*)d_in[2];
    const float* Wl1 = (const float*)d_in[4];
    const float* bl1 = (const float*)d_in[5];
    const float* Wr1 = (const float*)d_in[6];
    const float* br1 = (const float*)d_in[7];
    const float* We1 = (const float*)d_in[8];
    const float* att1 = (const float*)d_in[9];
    const float* bc1 = (const float*)d_in[10];
    const float* Wl2 = (const float*)d_in[11];
    const float* bl2 = (const float*)d_in[12];
    const float* Wr2 = (const float*)d_in[13];
    const float* br2 = (const float*)d_in[14];
    const float* We2 = (const float*)d_in[15];
    const float* att2 = (const float*)d_in[16];
    const float* bc2 = (const float*)d_in[17];
    const float* Wout = (const float*)d_in[18];
    const float* bout = (const float*)d_in[19];

    int N = in_sizes[0] / 64;
    int E = in_sizes[1] / 2;
    int M = E + N;
    const int* srcA = eidx;
    const int* dstA = eidx + E;

    char* w = (char*)d_ws;
    size_t used = 0;
    auto alloc = [&](size_t bytes) {
        char* p = w + used;
        used += (bytes + 255) & ~size_t(255);
        return p;
    };
    int*   cnt    = (int*)alloc((size_t)N * 4);
    int*   fill   = (int*)alloc((size_t)N * 4);
    int*   rowptr = (int*)alloc((size_t)(N + 1) * 4);
    int*   bsum   = (int*)alloc(1024 * 4);
    int*   ssrc   = (int*)alloc((size_t)M * 4);
    int*   sdst   = (int*)alloc((size_t)M * 4);
    int*   seid   = (int*)alloc((size_t)M * 4);
    float* escr   = (float*)alloc((size_t)M * 4);
    float* mattr  = (float*)alloc((size_t)N * 16 * 4);
    unsigned short* xl_b = (unsigned short*)alloc((size_t)N * 64 * 2);
    unsigned short* xr_b = (unsigned short*)alloc((size_t)N * 64 * 2);
    float* h1     = (float*)alloc((size_t)N * 64 * 4);
    size_t eperm_bytes = (size_t)M * 16 * 2;
    bool perm = (used + eperm_bytes) <= ws_size;
    unsigned short* eperm_b = perm ? (unsigned short*)alloc(eperm_bytes) : nullptr;

    hipMemsetAsync(cnt, 0, (size_t)N * 4, stream);
    hipMemsetAsync(fill, 0, (size_t)N * 4, stream);
    hipMemsetAsync(seid, 0xFF, (size_t)M * 4, stream);

    int NB = (N + 255) / 256;
    count_k<<<(E + 255) / 256, 256, 0, stream>>>(dstA, cnt, E);
    scan1_k<<<NB, 256, 0, stream>>>(cnt, rowptr, bsum, N);
    scan2_k<<<1, 1024, 0, stream>>>(bsum, NB);
    scan3_k<<<NB, 256, 0, stream>>>(rowptr, bsum, N, M);
    fill_k<<<(E + 255) / 256, 256, 0, stream>>>(srcA, dstA, rowptr, fill,
                                                ssrc, sdst, seid, E);

    if (perm) {
        permute_k<<<(M * 2 + 255) / 256, 256, 0, stream>>>(eattr, seid, eperm_b, M);
        mean_k<1><<<(N * 16 + 255) / 256, 256, 0, stream>>>(
            eattr, seid, rowptr, eperm_b, mattr, ssrc, sdst, N);
    } else {
        mean_k<0><<<(N * 16 + 255) / 256, 256, 0, stream>>>(
            eattr, seid, rowptr, nullptr, mattr, ssrc, sdst, N);
    }

    int nodeBlocks = (N + 3) / 4;
    int xfrmBlocks = (N + 31) / 32;     // 32 nodes per block (8 per wave)
    int slotBlocks = (M + 511) / 512;   // 512 slots per block (2 per lane)

    // ---- layer 1
    xfrm_k<<<xfrmBlocks, 256, 0, stream>>>(x, Wl1, bl1, Wr1, br1, xl_b, xr_b, N);
    if (perm)
        escore_k<1><<<slotBlocks, 256, 0, stream>>>(xl_b, xr_b, eperm_b, eattr, seid,
                                                    mattr, ssrc, sdst, We1, att1, escr, M);
    else
        escore_k<0><<<slotBlocks, 256, 0, stream>>>(xl_b, xr_b, nullptr, eattr, seid,
                                                    mattr, ssrc, sdst, We1, att1, escr, M);
    aggregate_k<0><<<nodeBlocks, 256, 0, stream>>>(xl_b, escr, ssrc, rowptr, bc1, h1,
                                                   nullptr, nullptr, nullptr, nullptr, N);

    // ---- layer 2 (+ fused JK-cat readout)
    xfrm_k<<<xfrmBlocks, 256, 0, stream>>>(h1, Wl2, bl2, Wr2, br2, xl_b, xr_b, N);
    if (perm)
        escore_k<1><<<slotBlocks, 256, 0, stream>>>(xl_b, xr_b, eperm_b, eattr, seid,
                                                    mattr, ssrc, sdst, We2, att2, escr, M);
    else
        escore_k<0><<<slotBlocks, 256, 0, stream>>>(xl_b, xr_b, nullptr, eattr, seid,
                                                    mattr, ssrc, sdst, We2, att2, escr, M);
    aggregate_k<1><<<nodeBlocks, 256, 0, stream>>>(xl_b, escr, ssrc, rowptr, bc2, nullptr,
                                                   h1, Wout, bout, (float*)d_out, N);
}